// Round 2
// baseline (832.659 us; speedup 1.0000x reference)
//
#include <hip/hip_runtime.h>
#include <stdint.h>

#define TT 96
#define SS 1024
#define BB 256
#define START_TAG 94
#define STOP_TAG 95
#define LOG2E 1.44269504088896340736f
#define LN2   0.69314718055994530942f

typedef float f32x2 __attribute__((ext_vector_type(2)));
typedef float f32x4 __attribute__((ext_vector_type(4)));

static __device__ __forceinline__ f32x2 fma2(f32x2 a, f32x2 b, f32x2 c) {
#if __has_builtin(__builtin_elementwise_fma)
    return __builtin_elementwise_fma(a, b, c);
#else
    f32x2 r; r.x = fmaf(a.x, b.x, c.x); r.y = fmaf(a.y, b.y, c.y); return r;
#endif
}

// ws: E2T[j*96 + i] = exp(trans[i][j])  (transposed exp-table, 36 KB)
__global__ void prep_kernel(const float* __restrict__ trans, float* __restrict__ E2T) {
    int idx = blockIdx.x * blockDim.x + threadIdx.x;
    if (idx < TT * TT) {
        int jj = idx / TT, ii = idx % TT;
        E2T[idx] = expf(trans[ii * TT + jj]);
    }
}

// One wave (64 threads) per batch. No s_barrier anywhere: intra-wave LDS
// ordering is in-order per wave; wave_barrier() only fences the compiler.
__global__ __launch_bounds__(64, 1) void forward_kernel(
    const float* __restrict__ features, const int* __restrict__ mask,
    const float* __restrict__ trans, const float* __restrict__ E2T,
    float* __restrict__ out)
{
    const int b  = blockIdx.x;
    const int l  = threadIdx.x;          // lane: owns col l (all) + col 64+(l&31)
    const int l2 = 64 + (l & 31);        // upper lanes duplicate lanes 0-31's work

    __shared__ __align__(16) float alpha[TT];

    // ---- sequence length from prefix mask ----
    const int* mb = mask + b * SS;
    int cnt = 0;
    #pragma unroll
    for (int i = 0; i < SS / 64; ++i) cnt += (mb[i * 64 + l] != 0);
    #pragma unroll
    for (int d = 1; d < 64; d <<= 1) cnt += __shfl_xor(cnt, d);
    const int len = cnt;                 // uniform across wave

    // ---- E column slices into registers (as pk pairs over i) ----
    f32x2 E0[48], E1[48];
    {
        const f32x4* e0p = reinterpret_cast<const f32x4*>(E2T + l * TT);
        const f32x4* e1p = reinterpret_cast<const f32x4*>(E2T + l2 * TT);
        #pragma unroll
        for (int k = 0; k < 24; ++k) {
            f32x4 a = e0p[k];
            E0[2 * k]     = __builtin_shufflevector(a, a, 0, 1);
            E0[2 * k + 1] = __builtin_shufflevector(a, a, 2, 3);
            f32x4 c = e1p[k];
            E1[2 * k]     = __builtin_shufflevector(c, c, 0, 1);
            E1[2 * k + 1] = __builtin_shufflevector(c, c, 2, 3);
        }
    }

    const float* fb = features + (size_t)b * SS * TT;
    float fA[8], gA[8], fN[8], gN[8];    // raw feature groups (current / next)
    float eA[8], eB[8];                  // exp2 of current group

    #pragma unroll
    for (int u = 0; u < 8; ++u) { fA[u] = fb[u * TT + l]; gA[u] = fb[u * TT + l2]; }

    // ---- t = 0 init ----
    {
        alpha[l] = exp2f((fA[0] + trans[START_TAG * TT + l]) * LOG2E);
        if (l < 32)
            alpha[l2] = exp2f((gA[0] + trans[START_TAG * TT + l2]) * LOG2E);
    }
    __builtin_amdgcn_wave_barrier();

    float c2 = 0.0f;      // accumulated log2 scale
    float pend = 1.0f;    // 2^-pe to fold into next step's emission factor
    int   pe = 0;

    const int ngr = (len + 7) >> 3;
    for (int g = 0; g < ngr; ++g) {
        // exp2 of current group's features (independent of the chain -> hoistable)
        #pragma unroll
        for (int u = 0; u < 8; ++u) {
            eA[u] = exp2f(fA[u] * LOG2E);
            eB[u] = exp2f(gA[u] * LOG2E);
        }
        // prefetch next group (clamped in-bounds)
        {
            int gbase = (g + 1) * 8; if (gbase > SS - 8) gbase = SS - 8;
            const float* fr = fb + gbase * TT;
            #pragma unroll
            for (int u = 0; u < 8; ++u) { fN[u] = fr[u * TT + l]; gN[u] = fr[u * TT + l2]; }
        }
        const int t0 = g * 8;
        #pragma unroll
        for (int u = 0; u < 8; ++u) {
            const int t = t0 + u;
            if (t > 0 && t < len) {      // uniform guard
                float ef0 = eA[u] * pend;
                float ef1 = eB[u] * pend;
                f32x2 s00 = 0.f, s01 = 0.f, s10 = 0.f, s11 = 0.f;
                const f32x4* ap = reinterpret_cast<const f32x4*>(alpha);
                #pragma unroll
                for (int k = 0; k < 24; ++k) {
                    f32x4 a4 = ap[k];                     // broadcast ds_read_b128
                    f32x2 lo = __builtin_shufflevector(a4, a4, 0, 1);
                    f32x2 hi = __builtin_shufflevector(a4, a4, 2, 3);
                    s00 = fma2(lo, E0[2 * k],     s00);
                    s01 = fma2(hi, E0[2 * k + 1], s01);
                    s10 = fma2(lo, E1[2 * k],     s10);
                    s11 = fma2(hi, E1[2 * k + 1], s11);
                }
                if (pe != 0) { c2 += (float)pe; pe = 0; pend = 1.0f; } // ef already captured pend
                f32x2 sA = s00 + s01;
                f32x2 sB = s10 + s11;
                float an0 = (sA.x + sA.y) * ef0;
                float an1 = (sB.x + sB.y) * ef1;
                __builtin_amdgcn_wave_barrier();
                alpha[l] = an0;
                if (l < 32) alpha[l2] = an1;
                __builtin_amdgcn_wave_barrier();
                if (u == 7) {
                    // exact power-of-2 renorm, applied next step
                    float m = fmaxf(an0, an1);
                    #pragma unroll
                    for (int d = 1; d < 64; d <<= 1) m = fmaxf(m, __shfl_xor(m, d));
                    int eb = (int)((__float_as_uint(m) >> 23) & 255u);
                    pe = eb - 127;
                    pend = __uint_as_float((uint32_t)((254 - eb) << 23));
                }
            }
        }
        #pragma unroll
        for (int u = 0; u < 8; ++u) { fA[u] = fN[u]; gA[u] = gN[u]; }
    }

    // ---- logZ_b = ln2 * (c2 + log2( sum_i alpha_i * exp(trans[i,STOP]) )) ----
    __builtin_amdgcn_wave_barrier();
    float v = alpha[l] * E2T[STOP_TAG * TT + l];
    float v2 = (l < 32) ? alpha[l2] * E2T[STOP_TAG * TT + l2] : 0.0f;
    v += v2;
    #pragma unroll
    for (int d = 1; d < 64; d <<= 1) v += __shfl_xor(v, d);
    if (l == 0) {
        float logZ = LN2 * (c2 + log2f(v));
        atomicAdd(out, logZ);
    }
}

__global__ void gold_kernel(const float* __restrict__ features, const int* __restrict__ mask,
                            const int* __restrict__ y, const float* __restrict__ trans,
                            float* __restrict__ out)
{
    int idx = blockIdx.x * blockDim.x + threadIdx.x;
    float e = 0.0f;
    if (idx < BB * SS) {
        int t = idx % SS;
        if (mask[idx] != 0) {
            int yt   = y[idx];
            int prev = (t == 0) ? START_TAG : y[idx - 1];
            e = features[(size_t)idx * TT + yt] + trans[prev * TT + yt];
            bool is_last = (t == SS - 1) || (mask[idx + 1] == 0);
            if (is_last) e += trans[yt * TT + STOP_TAG];
        }
    }
    #pragma unroll
    for (int d = 1; d < 64; d <<= 1) e += __shfl_xor(e, d);
    __shared__ float ws4[4];
    int lane = threadIdx.x & 63, wv = threadIdx.x >> 6;
    if (lane == 0) ws4[wv] = e;
    __syncthreads();
    if (threadIdx.x == 0) {
        float s = ws4[0] + ws4[1] + ws4[2] + ws4[3];
        atomicAdd(out, -s);
    }
}

extern "C" void kernel_launch(void* const* d_in, const int* in_sizes, int n_in,
                              void* d_out, int out_size, void* d_ws, size_t ws_size,
                              hipStream_t stream) {
    const float* features = (const float*)d_in[0];
    const int*   mask     = (const int*)d_in[1];
    const int*   y        = (const int*)d_in[2];
    const float* trans    = (const float*)d_in[3];
    float*       out      = (float*)d_out;
    float*       E2T      = (float*)d_ws;   // 96*96 floats = 36 KB

    hipMemsetAsync(d_out, 0, sizeof(float) * out_size, stream);
    prep_kernel<<<(TT * TT + 255) / 256, 256, 0, stream>>>(trans, E2T);
    forward_kernel<<<BB, 64, 0, stream>>>(features, mask, trans, E2T, out);
    gold_kernel<<<(BB * SS) / 256, 256, 0, stream>>>(features, mask, y, trans, out);
}

// Round 4
// 544.408 us; speedup vs baseline: 1.5295x; 1.5295x over previous
//
#include <hip/hip_runtime.h>
#include <stdint.h>

#define TT 96
#define SS 1024
#define BB 256
#define START_TAG 94
#define STOP_TAG 95
#define LOG2E 1.44269504088896340736f
#define LN2   0.69314718055994530942f

typedef float f32x4v __attribute__((ext_vector_type(4)));
typedef __bf16 bf16x8 __attribute__((ext_vector_type(8)));

// ---- fat-path ws layout (bytes) ----
#define EF_BYTES   50331648u          // 16 blk * 1024 t * 64 lane * 12 u32 * 4
#define ABUF_OFF   50331648u          // 18 tiles * 64 lanes * 4 u32  = 18432 B
#define ESTART_OFF 50350080u          // 64 * 24 f32 = 6144 B
#define ESTOP_OFF  50356224u          // 64 * 24 f32 = 6144 B
#define WS_NEED    50427904u          // + 64 KiB slack for prefetch overread

union U4B { uint4 u; bf16x8 v; };

static __device__ __forceinline__ uint32_t pk_bf16(float a, float b) {
    uint32_t r;
    asm("v_cvt_pk_bf16_f32 %0, %1, %2" : "=v"(r) : "v"(a), "v"(b));
    return r;
}

#define MFMA(a, b, c) __builtin_amdgcn_mfma_f32_16x16x32_bf16((a), (b), (c), 0, 0, 0)

// ---------------------------------------------------------------------------
// prep_consts: bake A-fragments (E^T in bf16, exact MFMA lane order), and
// Estart/Estop in the D-layout per-lane order.
//   A[m][k] = exp(trans[k][m]);  lane l: m = 16*mt + (l&15),
//   k = 32*kt + 16*(v>>1) + 4*(l>>4) + 2*(v&1) + {0,1} for word v.
// ---------------------------------------------------------------------------
__global__ __launch_bounds__(256) void prep_consts(const float* __restrict__ tr,
                                                   char* __restrict__ ws) {
    int i = blockIdx.x * 256 + threadIdx.x;
    if (i < 4608) {
        uint32_t* A = (uint32_t*)(ws + ABUF_OFF);
        int tile = i >> 8, rem = i & 255, l = rem >> 2, v = rem & 3;
        int mt = tile / 3, kt = tile - mt * 3;
        int hi = l >> 4, m = 16 * mt + (l & 15);
        int k0 = 32 * kt + 16 * (v >> 1) + 4 * hi + 2 * (v & 1);
        A[i] = pk_bf16(expf(tr[k0 * TT + m]), expf(tr[(k0 + 1) * TT + m]));
    } else if (i < 4608 + 2 * 1536) {
        int e = i - 4608;
        int stop = (e >= 1536) ? 1 : 0;
        if (stop) e -= 1536;
        int l = e / 24, c = e % 24;
        int mt = c >> 2, r = c & 3, hi = l >> 4;
        int j = 16 * mt + 4 * hi + r;
        float* dst = (float*)(ws + (stop ? ESTOP_OFF : ESTART_OFF));
        dst[e] = expf(stop ? tr[j * TT + STOP_TAG] : tr[START_TAG * TT + j]);
    }
}

// ---------------------------------------------------------------------------
// ef_kernel: EF[((blk*1024+t)*64+l)*12+q] = pk_bf16(exp(f[b][t][j0]), exp(f[b][t][j0+1]))
//   b = blk*16 + (l&15), j0 = 16*(q>>1) + 4*(l>>4) + 2*(q&1)
// ---------------------------------------------------------------------------
__global__ __launch_bounds__(256) void ef_kernel(const float* __restrict__ f,
                                                 uint32_t* __restrict__ ef) {
    int tid  = blockIdx.x * 256 + threadIdx.x;   // exact: 16*1024*64*12 threads
    int q    = tid % 12;
    int rest = tid / 12;
    int l    = rest & 63;
    int bt   = rest >> 6;
    int t    = bt & 1023;
    int blk  = bt >> 10;
    int b    = blk * 16 + (l & 15);
    int j0   = 16 * (q >> 1) + 4 * (l >> 4) + 2 * (q & 1);
    const float2* p = reinterpret_cast<const float2*>(f + (size_t)(b * SS + t) * TT + j0);
    float2 v = *p;
    ef[tid] = pk_bf16(expf(v.x), expf(v.y));
}

// ---------------------------------------------------------------------------
// fwd_kernel: blocks 0..15 = MFMA scan (16 batches each, 1 wave, no LDS, no
// barriers, per-batch renorm). blocks 16..255 = gold score.
// ---------------------------------------------------------------------------
__global__ __launch_bounds__(64, 1) void fwd_kernel(
    const float* __restrict__ features, const int* __restrict__ mask,
    const int* __restrict__ y, const float* __restrict__ trans,
    const char* __restrict__ ws, float* __restrict__ out)
{
    const int l = threadIdx.x;

    if (blockIdx.x >= 16) {
        // ---------------- gold part ----------------
        int bg = blockIdx.x - 16;
        float e = 0.f;
        #pragma unroll 1
        for (int k = 0; k < 18; ++k) {
            int idx = bg * 64 + l + k * 15360;
            if (idx < BB * SS) {
                int t = idx & (SS - 1);
                if (mask[idx]) {
                    int yt   = y[idx];
                    int prev = t ? y[idx - 1] : START_TAG;
                    e += features[(size_t)idx * TT + yt] + trans[prev * TT + yt];
                    bool last = (t == SS - 1) || (mask[idx + 1] == 0);
                    if (last) e += trans[yt * TT + STOP_TAG];
                }
            }
        }
        #pragma unroll
        for (int d = 1; d < 64; d <<= 1) e += __shfl_xor(e, d);
        if (l == 0) atomicAdd(out, -e);
        return;
    }

    // ---------------- scan part ----------------
    const int blk = blockIdx.x;
    const int n = l & 15, hi = l >> 4;

    // EF ring: 8 slots x 3 uint4, refilled one 8-step group ahead
    uint4 efr[8][3];
    const char* efp[8];
    {
        const char* base = ws + ((size_t)(blk * SS) * 64 + l) * 48;
        #pragma unroll
        for (int u = 0; u < 8; ++u) {
            const char* p = base + (size_t)u * 3072;
            efr[u][0] = *(const uint4*)(p);
            efr[u][1] = *(const uint4*)(p + 16);
            efr[u][2] = *(const uint4*)(p + 32);
            efp[u] = p + 8 * 3072;
        }
    }

    // length (lens guaranteed >= 512: count only t in [512,1024))
    int cnt = 0;
    {
        const int4* mrow = (const int4*)(mask + (blk * 16 + n) * SS + 512 + hi * 128);
        #pragma unroll
        for (int k = 0; k < 32; ++k) {
            int4 mv = mrow[k];
            cnt += mv.x + mv.y + mv.z + mv.w;
        }
        cnt += __shfl_xor(cnt, 16);
        cnt += __shfl_xor(cnt, 32);
    }
    const int len_m1 = cnt + 512 - 1;

    // constants
    bf16x8 Af[6][3];
    {
        const uint4* ab = (const uint4*)(ws + ABUF_OFF);
        #pragma unroll
        for (int mt = 0; mt < 6; ++mt)
            #pragma unroll
            for (int kt = 0; kt < 3; ++kt) {
                U4B ub; ub.u = ab[(mt * 3 + kt) * 64 + l];
                Af[mt][kt] = ub.v;
            }
    }
    float est[6][4];
    {
        const float4* es1 = (const float4*)(ws + ESTOP_OFF);
        #pragma unroll
        for (int mt = 0; mt < 6; ++mt) {
            float4 v = es1[l * 6 + mt];
            est[mt][0] = v.x; est[mt][1] = v.y; est[mt][2] = v.z; est[mt][3] = v.w;
        }
    }

    // per-batch scale state (uniform across the 4 lanes of batch n)
    float c2 = 0.f, pend = 1.0f, pe = 0.f, logz = 0.f;
    bf16x8 Bf[3];
    const f32x4v Z4 = {0.f, 0.f, 0.f, 0.f};

#define UNPACK12(CE0, CE1, CE2, EFV) { \
    uint32_t w_[12] = { CE0.x, CE0.y, CE0.z, CE0.w, CE1.x, CE1.y, CE1.z, CE1.w, \
                        CE2.x, CE2.y, CE2.z, CE2.w }; \
    _Pragma("unroll") \
    for (int q_ = 0; q_ < 12; ++q_) { \
        EFV[q_ >> 1][(q_ & 1) * 2]     = __uint_as_float(w_[q_] << 16); \
        EFV[q_ >> 1][(q_ & 1) * 2 + 1] = __uint_as_float(w_[q_] & 0xffff0000u); \
    } }

#define PACKB(AF) { \
    uint32_t wlo_[6], whi_[6]; \
    _Pragma("unroll") \
    for (int mt_ = 0; mt_ < 6; ++mt_) { \
        wlo_[mt_] = pk_bf16(AF[mt_][0], AF[mt_][1]); \
        whi_[mt_] = pk_bf16(AF[mt_][2], AF[mt_][3]); } \
    _Pragma("unroll") \
    for (int kt_ = 0; kt_ < 3; ++kt_) { \
        U4B ub_; ub_.u.x = wlo_[2 * kt_]; ub_.u.y = whi_[2 * kt_]; \
        ub_.u.z = wlo_[2 * kt_ + 1]; ub_.u.w = whi_[2 * kt_ + 1]; \
        Bf[kt_] = ub_.v; } }

    // init t = 0: alpha0 = EF0 * Estart
    {
        float esr[6][4];
        const float4* es0 = (const float4*)(ws + ESTART_OFF);
        #pragma unroll
        for (int mt = 0; mt < 6; ++mt) {
            float4 v = es0[l * 6 + mt];
            esr[mt][0] = v.x; esr[mt][1] = v.y; esr[mt][2] = v.z; esr[mt][3] = v.w;
        }
        float efv[6][4];
        UNPACK12(efr[0][0], efr[0][1], efr[0][2], efv);
        float af0[6][4];
        #pragma unroll
        for (int mt = 0; mt < 6; ++mt)
            #pragma unroll
            for (int r = 0; r < 4; ++r) af0[mt][r] = efv[mt][r] * esr[mt][r];
        PACKB(af0);
    }

// APPLY/REDUCE on every odd step: scale computed at odd t applied at t+2.
// Per-batch max via shfl_xor(16/32) only (batch n lives in lanes n,n+16,n+32,n+48).
#define STEP(u, ARED) { \
    uint4 ce0 = efr[u][0], ce1 = efr[u][1], ce2 = efr[u][2]; \
    { const char* p_ = efp[u]; \
      efr[u][0] = *(const uint4*)(p_); \
      efr[u][1] = *(const uint4*)(p_ + 16); \
      efr[u][2] = *(const uint4*)(p_ + 32); \
      efp[u] = p_ + 24576; } \
    f32x4v acc[6]; \
    _Pragma("unroll") \
    for (int mt_ = 0; mt_ < 6; ++mt_) { \
        acc[mt_] = MFMA(Af[mt_][0], Bf[0], Z4); \
        acc[mt_] = MFMA(Af[mt_][1], Bf[1], acc[mt_]); \
        acc[mt_] = MFMA(Af[mt_][2], Bf[2], acc[mt_]); } \
    if (ARED) { c2 += pe; } \
    float efv[6][4]; \
    UNPACK12(ce0, ce1, ce2, efv); \
    float af[6][4]; \
    _Pragma("unroll") \
    for (int mt_ = 0; mt_ < 6; ++mt_) \
        _Pragma("unroll") \
        for (int r_ = 0; r_ < 4; ++r_) { \
            float a_ = acc[mt_][r_]; \
            if (ARED) a_ *= pend; \
            af[mt_][r_] = a_ * efv[mt_][r_]; } \
    { int cap_ = (len_m1 == tb8 + (u)); \
      if (__any(cap_)) { \
          float d_ = 0.f; \
          _Pragma("unroll") \
          for (int mt_ = 0; mt_ < 6; ++mt_) \
              _Pragma("unroll") \
              for (int r_ = 0; r_ < 4; ++r_) d_ = fmaf(af[mt_][r_], est[mt_][r_], d_); \
          d_ += __shfl_xor(d_, 16); d_ += __shfl_xor(d_, 32); \
          float lz_ = LN2 * (c2 + log2f(d_)); \
          logz = cap_ ? lz_ : logz; } } \
    if (ARED) { \
        float m_[6]; \
        _Pragma("unroll") \
        for (int mt_ = 0; mt_ < 6; ++mt_) \
            m_[mt_] = fmaxf(fmaxf(af[mt_][0], af[mt_][1]), fmaxf(af[mt_][2], af[mt_][3])); \
        float mm_ = fmaxf(fmaxf(fmaxf(m_[0], m_[1]), fmaxf(m_[2], m_[3])), fmaxf(m_[4], m_[5])); \
        mm_ = fmaxf(mm_, __shfl_xor(mm_, 16)); \
        mm_ = fmaxf(mm_, __shfl_xor(mm_, 32)); \
        unsigned eb_ = (__float_as_uint(mm_) >> 23) & 255u; \
        pe = (float)((int)eb_ - 127); \
        pend = __uint_as_float((254u - eb_) << 23); } \
    PACKB(af); }

    int tb8 = 0;
    // body tb = 0 (t=0 already consumed; just refill slot 0)
    {
        const char* p_ = efp[0];
        efr[0][0] = *(const uint4*)(p_);
        efr[0][1] = *(const uint4*)(p_ + 16);
        efr[0][2] = *(const uint4*)(p_ + 32);
        efp[0] = p_ + 24576;
    }
    STEP(1, 1) STEP(2, 0) STEP(3, 1) STEP(4, 0)
    STEP(5, 1) STEP(6, 0) STEP(7, 1)
    tb8 = 8;
    #pragma unroll 1
    for (int tb = 1; tb < 128; ++tb, tb8 += 8) {
        STEP(0, 0) STEP(1, 1) STEP(2, 0) STEP(3, 1)
        STEP(4, 0) STEP(5, 1) STEP(6, 0) STEP(7, 1)
    }

    if (l < 16) atomicAdd(out, logz);
#undef STEP
#undef PACKB
#undef UNPACK12
}

// ===========================================================================
// Fallback path (ws too small): R1's verified kernels.
// ===========================================================================
__global__ void fb_prep(const float* __restrict__ trans, float* __restrict__ E2T) {
    int idx = blockIdx.x * blockDim.x + threadIdx.x;
    if (idx < TT * TT) {
        int jj = idx / TT, ii = idx % TT;
        E2T[idx] = expf(trans[ii * TT + jj]);
    }
}

__global__ __launch_bounds__(384) void fb_forward(
    const float* __restrict__ features, const int* __restrict__ mask,
    const float* __restrict__ trans, const float* __restrict__ E2T,
    float* __restrict__ out)
{
    const int b    = blockIdx.x;
    const int tid  = threadIdx.x;
    const int j    = tid >> 2;
    const int q    = tid & 3;
    const int lane = tid & 63;
    const int wv   = tid >> 6;

    __shared__ float alpha[2][TT];
    __shared__ float fch[2][16 * TT];
    __shared__ float wred[6];
    __shared__ int   wcnt[6];
    __shared__ int   len_sh;

    int cnt = 0;
    for (int i = tid; i < SS; i += 384) cnt += (mask[b * SS + i] != 0);
    #pragma unroll
    for (int d = 1; d < 64; d <<= 1) cnt += __shfl_xor(cnt, d);
    if (lane == 0) wcnt[wv] = cnt;
    __syncthreads();
    if (tid == 0) {
        int L = 0;
        for (int w = 0; w < 6; ++w) L += wcnt[w];
        len_sh = L;
    }

    float Er[24];
    {
        const float4* ep = reinterpret_cast<const float4*>(E2T + j * TT + q * 24);
        #pragma unroll
        for (int k = 0; k < 6; ++k) {
            float4 e4 = ep[k];
            Er[4*k+0] = e4.x; Er[4*k+1] = e4.y; Er[4*k+2] = e4.z; Er[4*k+3] = e4.w;
        }
    }

    const float* fb = features + (size_t)b * SS * TT;
    float4 r0    = reinterpret_cast<const float4*>(fb)[tid];
    float4 rnext = reinterpret_cast<const float4*>(fb + 16 * TT)[tid];
    reinterpret_cast<float4*>(&fch[0][0])[tid] = r0;
    __syncthreads();
    const int len = len_sh;

    if (q == 0) {
        float p0 = fch[0][j] + trans[START_TAG * TT + j];
        alpha[0][j] = exp2f(p0 * LOG2E);
    }
    __syncthreads();

    float c2 = 0.0f;
    float pending = 1.0f;
    int   pe = 0;

    const int clast = (len - 1) >> 4;
    for (int c = 0; c <= clast; ++c) {
        if (c > 0) {
            reinterpret_cast<float4*>(&fch[c & 1][0])[tid] = rnext;
            int cn = c + 1; if (cn > SS / 16 - 1) cn = SS / 16 - 1;
            rnext = reinterpret_cast<const float4*>(fb + cn * 16 * TT)[tid];
            __syncthreads();
        }
        const int t0   = c * 16;
        const int tbeg = (c == 0) ? 1 : t0;
        int tend = t0 + 16; if (tend > len) tend = len;

        for (int t = tbeg; t < tend; ++t) {
            const float* acur = alpha[(t + 1) & 1];
            const float4* ap = reinterpret_cast<const float4*>(acur + q * 24);
            float sum = 0.0f;
            #pragma unroll
            for (int k = 0; k < 6; ++k) {
                float4 a = ap[k];
                sum = fmaf(Er[4*k+0], a.x, sum);
                sum = fmaf(Er[4*k+1], a.y, sum);
                sum = fmaf(Er[4*k+2], a.z, sum);
                sum = fmaf(Er[4*k+3], a.w, sum);
            }
            sum += __shfl_xor(sum, 1);
            sum += __shfl_xor(sum, 2);

            float f    = fch[c & 1][(t - t0) * TT + j];
            float anew = sum * exp2f(f * LOG2E) * pending;
            c2 += (float)pe; pe = 0; pending = 1.0f;

            if (q == 0) alpha[t & 1][j] = anew;
            if ((t & 3) == 3) {
                float m = anew;
                m = fmaxf(m, __shfl_xor(m, 4));
                m = fmaxf(m, __shfl_xor(m, 8));
                m = fmaxf(m, __shfl_xor(m, 16));
                m = fmaxf(m, __shfl_xor(m, 32));
                if (lane == 0) wred[wv] = m;
            }
            __syncthreads();
            if ((t & 3) == 3) {
                float mv = wred[0];
                #pragma unroll
                for (int w = 1; w < 6; ++w) mv = fmaxf(mv, wred[w]);
                int eb  = (int)((__float_as_uint(mv) >> 23) & 255u);
                pe      = eb - 127;
                pending = __uint_as_float((uint32_t)(254 - eb) << 23);
            }
        }
    }

    float v = 0.0f;
    if (q == 0) v = alpha[(len - 1) & 1][j] * E2T[STOP_TAG * TT + j];
    #pragma unroll
    for (int d = 1; d < 64; d <<= 1) v += __shfl_xor(v, d);
    __syncthreads();
    if (lane == 0) wred[wv] = v;
    __syncthreads();
    if (tid == 0) {
        float tot = 0.0f;
        for (int w = 0; w < 6; ++w) tot += wred[w];
        atomicAdd(out, LN2 * (c2 + log2f(tot)));
    }
}

__global__ void fb_gold(const float* __restrict__ features, const int* __restrict__ mask,
                        const int* __restrict__ y, const float* __restrict__ trans,
                        float* __restrict__ out)
{
    int idx = blockIdx.x * blockDim.x + threadIdx.x;
    float e = 0.0f;
    if (idx < BB * SS) {
        int t = idx % SS;
        if (mask[idx] != 0) {
            int yt   = y[idx];
            int prev = (t == 0) ? START_TAG : y[idx - 1];
            e = features[(size_t)idx * TT + yt] + trans[prev * TT + yt];
            bool is_last = (t == SS - 1) || (mask[idx + 1] == 0);
            if (is_last) e += trans[yt * TT + STOP_TAG];
        }
    }
    #pragma unroll
    for (int d = 1; d < 64; d <<= 1) e += __shfl_xor(e, d);
    __shared__ float ws4[4];
    int lane = threadIdx.x & 63, wv = threadIdx.x >> 6;
    if (lane == 0) ws4[wv] = e;
    __syncthreads();
    if (threadIdx.x == 0) {
        float s = ws4[0] + ws4[1] + ws4[2] + ws4[3];
        atomicAdd(out, -s);
    }
}

extern "C" void kernel_launch(void* const* d_in, const int* in_sizes, int n_in,
                              void* d_out, int out_size, void* d_ws, size_t ws_size,
                              hipStream_t stream) {
    const float* features = (const float*)d_in[0];
    const int*   mask     = (const int*)d_in[1];
    const int*   y        = (const int*)d_in[2];
    const float* trans    = (const float*)d_in[3];
    float*       out      = (float*)d_out;

    hipMemsetAsync(d_out, 0, sizeof(float) * out_size, stream);

    if (ws_size >= WS_NEED) {
        char* ws = (char*)d_ws;
        prep_consts<<<30, 256, 0, stream>>>(trans, ws);
        ef_kernel<<<49152, 256, 0, stream>>>(features, (uint32_t*)ws);
        fwd_kernel<<<256, 64, 0, stream>>>(features, mask, y, trans, ws, out);
    } else {
        float* E2T = (float*)d_ws;
        fb_prep<<<(TT * TT + 255) / 256, 256, 0, stream>>>(trans, E2T);
        fb_forward<<<BB, 384, 0, stream>>>(features, mask, trans, E2T, out);
        fb_gold<<<(BB * SS) / 256, 256, 0, stream>>>(features, mask, y, trans, out);
    }
}

// Round 6
// 538.869 us; speedup vs baseline: 1.5452x; 1.0103x over previous
//
#include <hip/hip_runtime.h>
#include <stdint.h>

#define TT 96
#define SS 1024
#define BB 256
#define START_TAG 94
#define STOP_TAG 95
#define LOG2E 1.44269504088896340736f
#define LN2   0.69314718055994530942f

typedef float f32x2 __attribute__((ext_vector_type(2)));
typedef float f32x4v __attribute__((ext_vector_type(4)));
typedef __bf16 bf16x8 __attribute__((ext_vector_type(8)));

// ---- fat-path ws layout (bytes) ----
#define EF_BYTES   50331648u          // 16 blk * 1024 t * 3072 B
#define ABUF_OFF   50331648u
#define ESTART_OFF 50350080u
#define ESTOP_OFF  50356224u
#define WS_NEED    50427904u

union U4B { uint4 u; bf16x8 v; };

static __device__ __forceinline__ uint32_t pk_bf16(float a, float b) {
    uint32_t r;
    asm("v_cvt_pk_bf16_f32 %0, %1, %2" : "=v"(r) : "v"(a), "v"(b));
    return r;
}
static __device__ __forceinline__ f32x2 pmax2(f32x2 a, f32x2 b) {
#if __has_builtin(__builtin_elementwise_max)
    return __builtin_elementwise_max(a, b);
#else
    f32x2 r; r.x = fmaxf(a.x, b.x); r.y = fmaxf(a.y, b.y); return r;
#endif
}

#define MFMA(a, b, c) __builtin_amdgcn_mfma_f32_16x16x32_bf16((a), (b), (c), 0, 0, 0)
#define GLD(srcp, dstp) __builtin_amdgcn_global_load_lds( \
    (const __attribute__((address_space(1))) uint32_t*)(srcp), \
    (__attribute__((address_space(3))) uint32_t*)(dstp), 16, 0, 0)

// ---------------------------------------------------------------------------
// prep_consts (verified R4): A-fragments of E^T (bf16, MFMA lane order) +
// Estart/Estop in D-layout lane order.
// ---------------------------------------------------------------------------
__global__ __launch_bounds__(256) void prep_consts(const float* __restrict__ tr,
                                                   char* __restrict__ ws) {
    int i = blockIdx.x * 256 + threadIdx.x;
    if (i < 4608) {
        uint32_t* A = (uint32_t*)(ws + ABUF_OFF);
        int tile = i >> 8, rem = i & 255, l = rem >> 2, v = rem & 3;
        int mt = tile / 3, kt = tile - mt * 3;
        int hi = l >> 4, m = 16 * mt + (l & 15);
        int k0 = 32 * kt + 16 * (v >> 1) + 4 * hi + 2 * (v & 1);
        A[i] = pk_bf16(expf(tr[k0 * TT + m]), expf(tr[(k0 + 1) * TT + m]));
    } else if (i < 4608 + 2 * 1536) {
        int e = i - 4608;
        int stop = (e >= 1536) ? 1 : 0;
        if (stop) e -= 1536;
        int l = e / 24, c = e % 24;
        int mt = c >> 2, r = c & 3, hi = l >> 4;
        int j = 16 * mt + 4 * hi + r;
        float* dst = (float*)(ws + (stop ? ESTOP_OFF : ESTART_OFF));
        dst[e] = expf(stop ? tr[j * TT + STOP_TAG] : tr[START_TAG * TT + j]);
    }
}

// ---------------------------------------------------------------------------
// ef_kernel2: float4 in, uint2 out. word q at ef[r*12+q], q=2p,2p+1,
// j0(q)=16*(q>>1)+4*hi+2*(q&1) -> one float4 covers both words.
// ---------------------------------------------------------------------------
__global__ __launch_bounds__(256) void ef_kernel2(const float* __restrict__ f,
                                                  uint32_t* __restrict__ ef) {
    int tid = blockIdx.x * 256 + threadIdx.x;   // exact: 16*1024*64*6
    int p   = tid % 6;
    int r   = tid / 6;
    int l   = r & 63;
    int bt  = r >> 6;
    int t   = bt & 1023;
    int blk = bt >> 10;
    int b   = blk * 16 + (l & 15);
    int hi  = l >> 4;
    const float4* fp = (const float4*)(f + (size_t)(b * SS + t) * TT + 16 * p + 4 * hi);
    float4 v = *fp;
    uint2 w;
    w.x = pk_bf16(expf(v.x), expf(v.y));
    w.y = pk_bf16(expf(v.z), expf(v.w));
    *(uint2*)(ef + (size_t)r * 12 + 2 * p) = w;
}

// ---------------------------------------------------------------------------
// fwd_kernel: blocks 0..15 = MFMA scan, LDS-DMA EF ring, counted vmcnt.
// blocks 16..255 = gold score.
// ---------------------------------------------------------------------------
__global__ __launch_bounds__(64, 1) void fwd_kernel(
    const float* __restrict__ features, const int* __restrict__ mask,
    const int* __restrict__ y, const float* __restrict__ trans,
    const char* __restrict__ ws, float* __restrict__ out)
{
    const int l = threadIdx.x;

    if (blockIdx.x >= 16) {
        int bg = blockIdx.x - 16;
        float e = 0.f;
        #pragma unroll 1
        for (int k = 0; k < 18; ++k) {
            int idx = bg * 64 + l + k * 15360;
            if (idx < BB * SS) {
                int t = idx & (SS - 1);
                if (mask[idx]) {
                    int yt   = y[idx];
                    int prev = t ? y[idx - 1] : START_TAG;
                    e += features[(size_t)idx * TT + yt] + trans[prev * TT + yt];
                    bool last = (t == SS - 1) || (mask[idx + 1] == 0);
                    if (last) e += trans[yt * TT + STOP_TAG];
                }
            }
        }
        #pragma unroll
        for (int d = 1; d < 64; d <<= 1) e += __shfl_xor(e, d);
        if (l == 0) atomicAdd(out, -e);
        return;
    }

    __shared__ __align__(16) char ring[16 * 3072];
    char* ringc = (char*)ring;

    const int blk = blockIdx.x;
    const int n = l & 15;

    // ---- length ----
    int cnt = 0;
    {
        const int4* mrow = (const int4*)(mask + (blk * 16 + n) * SS + 512 + (l >> 4) * 128);
        #pragma unroll
        for (int k = 0; k < 32; ++k) {
            int4 mv = mrow[k];
            cnt += mv.x + mv.y + mv.z + mv.w;
        }
        cnt += __shfl_xor(cnt, 16);
        cnt += __shfl_xor(cnt, 32);
    }
    const int len_m1 = cnt + 512 - 1;

    // ---- constants ----
    bf16x8 Af[6][3];
    {
        const uint4* ab = (const uint4*)(ws + ABUF_OFF);
        #pragma unroll
        for (int mt = 0; mt < 6; ++mt)
            #pragma unroll
            for (int kt = 0; kt < 3; ++kt) {
                U4B ub; ub.u = ab[(mt * 3 + kt) * 64 + l];
                Af[mt][kt] = ub.v;
            }
    }
    f32x2 estL[6], estH[6];
    {
        const float4* es1 = (const float4*)(ws + ESTOP_OFF);
        #pragma unroll
        for (int mt = 0; mt < 6; ++mt) {
            float4 v = es1[l * 6 + mt];
            estL[mt].x = v.x; estL[mt].y = v.y;
            estH[mt].x = v.z; estH[mt].y = v.w;
        }
    }
    f32x2 esrL[6], esrH[6];
    {
        const float4* es0 = (const float4*)(ws + ESTART_OFF);
        #pragma unroll
        for (int mt = 0; mt < 6; ++mt) {
            float4 v = es0[l * 6 + mt];
            esrL[mt].x = v.x; esrL[mt].y = v.y;
            esrH[mt].x = v.z; esrH[mt].y = v.w;
        }
    }

    // ---- DMA prologue: slots 0..7 ----
    const char* efg = ws + (size_t)blk * SS * 3072 + l * 16;
    #pragma unroll
    for (int s = 0; s < 8; ++s) {
        const char* sp = efg + s * 3072;
        char* dp = ringc + s * 3072;
        GLD(sp, dp); GLD(sp + 1024, dp + 1024); GLD(sp + 2048, dp + 2048);
    }
    asm volatile("s_waitcnt vmcnt(0)" ::: "memory");

    uint4 PA[3], PB[3];
    {
        const uint4* rp = (const uint4*)(ringc + l * 48);
        PA[0] = rp[0]; PA[1] = rp[1]; PA[2] = rp[2];
        const uint4* rq = (const uint4*)(ringc + 3072 + l * 48);
        PB[0] = rq[0]; PB[1] = rq[1]; PB[2] = rq[2];
    }

    // per-batch scale state
    float c2 = 0.f, pe = 0.f, logz = 0.f;
    f32x2 pend2; pend2.x = 1.f; pend2.y = 1.f;
    bf16x8 Bf[3];
    const f32x4v Z4 = {0.f, 0.f, 0.f, 0.f};

#define UNPACKP(PBUF, EFP) { \
    uint32_t w_[12] = { PBUF[0].x, PBUF[0].y, PBUF[0].z, PBUF[0].w, \
                        PBUF[1].x, PBUF[1].y, PBUF[1].z, PBUF[1].w, \
                        PBUF[2].x, PBUF[2].y, PBUF[2].z, PBUF[2].w }; \
    _Pragma("unroll") \
    for (int q_ = 0; q_ < 12; ++q_) { \
        EFP[q_ >> 1][q_ & 1].x = __uint_as_float(w_[q_] << 16); \
        EFP[q_ >> 1][q_ & 1].y = __uint_as_float(w_[q_] & 0xffff0000u); \
    } }

#define PACKB2(AFL, AFH) { \
    uint32_t wlo_[6], whi_[6]; \
    _Pragma("unroll") \
    for (int mt_ = 0; mt_ < 6; ++mt_) { \
        wlo_[mt_] = pk_bf16(AFL[mt_].x, AFL[mt_].y); \
        whi_[mt_] = pk_bf16(AFH[mt_].x, AFH[mt_].y); } \
    _Pragma("unroll") \
    for (int kt_ = 0; kt_ < 3; ++kt_) { \
        U4B ub_; ub_.u.x = wlo_[2 * kt_]; ub_.u.y = whi_[2 * kt_]; \
        ub_.u.z = wlo_[2 * kt_ + 1]; ub_.u.w = whi_[2 * kt_ + 1]; \
        Bf[kt_] = ub_.v; } }

    // ---- init t = 0 (consumes PA/slot0; issues slot 8; reads slot 2 -> PA) ----
    {
        {
            const char* sp = efg + 8 * 3072;
            char* dp = ringc + 8 * 3072;
            GLD(sp, dp); GLD(sp + 1024, dp + 1024); GLD(sp + 2048, dp + 2048);
        }
        f32x2 efp[6][2];
        UNPACKP(PA, efp);
        f32x2 afL[6], afH[6];
        #pragma unroll
        for (int mt = 0; mt < 6; ++mt) {
            afL[mt] = efp[mt][0] * esrL[mt];
            afH[mt] = efp[mt][1] * esrH[mt];
        }
        PACKB2(afL, afH);
        asm volatile("s_waitcnt vmcnt(18)" ::: "memory");
        const uint4* rp = (const uint4*)(ringc + 2 * 3072 + l * 48);
        PA[0] = rp[0]; PA[1] = rp[1]; PA[2] = rp[2];
    }

#define STEP(PBUF, TCUR, APPLY, ARED) { \
    const int t_ = (TCUR); \
    { int ts_ = t_ + 8; if (ts_ > 1023) ts_ = 1023; \
      const char* sp_ = efg + (size_t)ts_ * 3072; \
      char* dp_ = ringc + ((t_ + 8) & 15) * 3072; \
      GLD(sp_, dp_); GLD(sp_ + 1024, dp_ + 1024); GLD(sp_ + 2048, dp_ + 2048); } \
    f32x4v acc[6]; \
    _Pragma("unroll") \
    for (int mt_ = 0; mt_ < 6; ++mt_) { \
        acc[mt_] = MFMA(Af[mt_][0], Bf[0], Z4); \
        acc[mt_] = MFMA(Af[mt_][1], Bf[1], acc[mt_]); \
        acc[mt_] = MFMA(Af[mt_][2], Bf[2], acc[mt_]); } \
    f32x2 efp[6][2]; \
    UNPACKP(PBUF, efp); \
    f32x2 afL[6], afH[6]; \
    _Pragma("unroll") \
    for (int mt_ = 0; mt_ < 6; ++mt_) { \
        f32x2 aL_, aH_; \
        aL_.x = acc[mt_][0]; aL_.y = acc[mt_][1]; \
        aH_.x = acc[mt_][2]; aH_.y = acc[mt_][3]; \
        if (APPLY) { aL_ = aL_ * pend2; aH_ = aH_ * pend2; } \
        afL[mt_] = aL_ * efp[mt_][0]; \
        afH[mt_] = aH_ * efp[mt_][1]; } \
    if (APPLY) { c2 += pe; } \
    asm volatile("s_waitcnt vmcnt(18)" ::: "memory"); \
    { const uint4* rp_ = (const uint4*)(ringc + ((t_ + 2) & 15) * 3072 + l * 48); \
      PBUF[0] = rp_[0]; PBUF[1] = rp_[1]; PBUF[2] = rp_[2]; } \
    PACKB2(afL, afH); \
    { int cap_ = (len_m1 == t_); \
      if (__any(cap_)) { \
          f32x2 ds_ = afL[0] * estL[0]; \
          ds_ = ds_ + afH[0] * estH[0]; \
          _Pragma("unroll") \
          for (int mt_ = 1; mt_ < 6; ++mt_) { \
              ds_ = ds_ + afL[mt_] * estL[mt_]; \
              ds_ = ds_ + afH[mt_] * estH[mt_]; } \
          float dd_ = ds_.x + ds_.y; \
          dd_ += __shfl_xor(dd_, 16); dd_ += __shfl_xor(dd_, 32); \
          float lz_ = LN2 * (c2 + log2f(dd_)); \
          logz = cap_ ? lz_ : logz; } } \
    if (ARED) { \
        f32x2 mp_ = pmax2(afL[0], afH[0]); \
        _Pragma("unroll") \
        for (int mt_ = 1; mt_ < 6; ++mt_) \
            mp_ = pmax2(mp_, pmax2(afL[mt_], afH[mt_])); \
        float mm_ = fmaxf(mp_.x, mp_.y); \
        mm_ = fmaxf(mm_, __shfl_xor(mm_, 16)); \
        mm_ = fmaxf(mm_, __shfl_xor(mm_, 32)); \
        unsigned eb_ = (__float_as_uint(mm_) >> 23) & 255u; \
        pe = (float)((int)eb_ - 127); \
        float pn_ = __uint_as_float((254u - eb_) << 23); \
        pend2.x = pn_; pend2.y = pn_; } }

    // head steps t = 1,2,3
    STEP(PB, 1, 1, 0)
    STEP(PA, 2, 0, 0)
    STEP(PB, 3, 0, 1)
    #pragma unroll 1
    for (int tb = 1; tb < 256; ++tb) {
        const int t4 = tb * 4;
        STEP(PA, t4 + 0, 0, 0)
        STEP(PB, t4 + 1, 1, 0)
        STEP(PA, t4 + 2, 0, 0)
        STEP(PB, t4 + 3, 0, 1)
    }

    if (l < 16) atomicAdd(out, logz);
#undef STEP
#undef PACKB2
#undef UNPACKP
}

// ===========================================================================
// Fallback path (ws too small): R1's verified kernels.
// ===========================================================================
__global__ void fb_prep(const float* __restrict__ trans, float* __restrict__ E2T) {
    int idx = blockIdx.x * blockDim.x + threadIdx.x;
    if (idx < TT * TT) {
        int jj = idx / TT, ii = idx % TT;
        E2T[idx] = expf(trans[ii * TT + jj]);
    }
}

__global__ __launch_bounds__(384) void fb_forward(
    const float* __restrict__ features, const int* __restrict__ mask,
    const float* __restrict__ trans, const float* __restrict__ E2T,
    float* __restrict__ out)
{
    const int b    = blockIdx.x;
    const int tid  = threadIdx.x;
    const int j    = tid >> 2;
    const int q    = tid & 3;
    const int lane = tid & 63;
    const int wv   = tid >> 6;

    __shared__ float alpha[2][TT];
    __shared__ float fch[2][16 * TT];
    __shared__ float wred[6];
    __shared__ int   wcnt[6];
    __shared__ int   len_sh;

    int cnt = 0;
    for (int i = tid; i < SS; i += 384) cnt += (mask[b * SS + i] != 0);
    #pragma unroll
    for (int d = 1; d < 64; d <<= 1) cnt += __shfl_xor(cnt, d);
    if (lane == 0) wcnt[wv] = cnt;
    __syncthreads();
    if (tid == 0) {
        int L = 0;
        for (int w = 0; w < 6; ++w) L += wcnt[w];
        len_sh = L;
    }

    float Er[24];
    {
        const float4* ep = reinterpret_cast<const float4*>(E2T + j * TT + q * 24);
        #pragma unroll
        for (int k = 0; k < 6; ++k) {
            float4 e4 = ep[k];
            Er[4*k+0] = e4.x; Er[4*k+1] = e4.y; Er[4*k+2] = e4.z; Er[4*k+3] = e4.w;
        }
    }

    const float* fb = features + (size_t)b * SS * TT;
    float4 r0    = reinterpret_cast<const float4*>(fb)[tid];
    float4 rnext = reinterpret_cast<const float4*>(fb + 16 * TT)[tid];
    reinterpret_cast<float4*>(&fch[0][0])[tid] = r0;
    __syncthreads();
    const int len = len_sh;

    if (q == 0) {
        float p0 = fch[0][j] + trans[START_TAG * TT + j];
        alpha[0][j] = exp2f(p0 * LOG2E);
    }
    __syncthreads();

    float c2 = 0.0f;
    float pending = 1.0f;
    int   pe = 0;

    const int clast = (len - 1) >> 4;
    for (int c = 0; c <= clast; ++c) {
        if (c > 0) {
            reinterpret_cast<float4*>(&fch[c & 1][0])[tid] = rnext;
            int cn = c + 1; if (cn > SS / 16 - 1) cn = SS / 16 - 1;
            rnext = reinterpret_cast<const float4*>(fb + cn * 16 * TT)[tid];
            __syncthreads();
        }
        const int t0   = c * 16;
        const int tbeg = (c == 0) ? 1 : t0;
        int tend = t0 + 16; if (tend > len) tend = len;

        for (int t = tbeg; t < tend; ++t) {
            const float* acur = alpha[(t + 1) & 1];
            const float4* ap = reinterpret_cast<const float4*>(acur + q * 24);
            float sum = 0.0f;
            #pragma unroll
            for (int k = 0; k < 6; ++k) {
                float4 a = ap[k];
                sum = fmaf(Er[4*k+0], a.x, sum);
                sum = fmaf(Er[4*k+1], a.y, sum);
                sum = fmaf(Er[4*k+2], a.z, sum);
                sum = fmaf(Er[4*k+3], a.w, sum);
            }
            sum += __shfl_xor(sum, 1);
            sum += __shfl_xor(sum, 2);

            float f    = fch[c & 1][(t - t0) * TT + j];
            float anew = sum * exp2f(f * LOG2E) * pending;
            c2 += (float)pe; pe = 0; pending = 1.0f;

            if (q == 0) alpha[t & 1][j] = anew;
            if ((t & 3) == 3) {
                float m = anew;
                m = fmaxf(m, __shfl_xor(m, 4));
                m = fmaxf(m, __shfl_xor(m, 8));
                m = fmaxf(m, __shfl_xor(m, 16));
                m = fmaxf(m, __shfl_xor(m, 32));
                if (lane == 0) wred[wv] = m;
            }
            __syncthreads();
            if ((t & 3) == 3) {
                float mv = wred[0];
                #pragma unroll
                for (int w = 1; w < 6; ++w) mv = fmaxf(mv, wred[w]);
                int eb  = (int)((__float_as_uint(mv) >> 23) & 255u);
                pe      = eb - 127;
                pending = __uint_as_float((uint32_t)(254 - eb) << 23);
            }
        }
    }

    float v = 0.0f;
    if (q == 0) v = alpha[(len - 1) & 1][j] * E2T[STOP_TAG * TT + j];
    #pragma unroll
    for (int d = 1; d < 64; d <<= 1) v += __shfl_xor(v, d);
    __syncthreads();
    if (lane == 0) wred[wv] = v;
    __syncthreads();
    if (tid == 0) {
        float tot = 0.0f;
        for (int w = 0; w < 6; ++w) tot += wred[w];
        atomicAdd(out, LN2 * (c2 + log2f(tot)));
    }
}

__global__ void fb_gold(const float* __restrict__ features, const int* __restrict__ mask,
                        const int* __restrict__ y, const float* __restrict__ trans,
                        float* __restrict__ out)
{
    int idx = blockIdx.x * blockDim.x + threadIdx.x;
    float e = 0.0f;
    if (idx < BB * SS) {
        int t = idx % SS;
        if (mask[idx] != 0) {
            int yt   = y[idx];
            int prev = (t == 0) ? START_TAG : y[idx - 1];
            e = features[(size_t)idx * TT + yt] + trans[prev * TT + yt];
            bool is_last = (t == SS - 1) || (mask[idx + 1] == 0);
            if (is_last) e += trans[yt * TT + STOP_TAG];
        }
    }
    #pragma unroll
    for (int d = 1; d < 64; d <<= 1) e += __shfl_xor(e, d);
    __shared__ float ws4[4];
    int lane = threadIdx.x & 63, wv = threadIdx.x >> 6;
    if (lane == 0) ws4[wv] = e;
    __syncthreads();
    if (threadIdx.x == 0) {
        float s = ws4[0] + ws4[1] + ws4[2] + ws4[3];
        atomicAdd(out, -s);
    }
}

extern "C" void kernel_launch(void* const* d_in, const int* in_sizes, int n_in,
                              void* d_out, int out_size, void* d_ws, size_t ws_size,
                              hipStream_t stream) {
    const float* features = (const float*)d_in[0];
    const int*   mask     = (const int*)d_in[1];
    const int*   y        = (const int*)d_in[2];
    const float* trans    = (const float*)d_in[3];
    float*       out      = (float*)d_out;

    hipMemsetAsync(d_out, 0, sizeof(float) * out_size, stream);

    if (ws_size >= WS_NEED) {
        char* ws = (char*)d_ws;
        prep_consts<<<30, 256, 0, stream>>>(trans, ws);
        ef_kernel2<<<24576, 256, 0, stream>>>(features, (uint32_t*)ws);
        fwd_kernel<<<256, 64, 0, stream>>>(features, mask, y, trans, ws, out);
    } else {
        float* E2T = (float*)d_ws;
        fb_prep<<<(TT * TT + 255) / 256, 256, 0, stream>>>(trans, E2T);
        fb_forward<<<BB, 384, 0, stream>>>(features, mask, trans, E2T, out);
        fb_gold<<<(BB * SS) / 256, 256, 0, stream>>>(features, mask, y, trans, out);
    }
}